// Round 7
// baseline (250.990 us; speedup 1.0000x reference)
//
#include <hip/hip_runtime.h>
#include <hip/hip_bf16.h>

#define DM    768
#define HEADS 12
#define DK    64
#define SEQ   2048
#define BATCH 4
#define NE    ((size_t)BATCH * SEQ * DM)   // 6,291,456
#define KT    12                           // 768/64 k-tiles per row-block
#define BRICK 8192                         // 128 rows x 64 k shorts per tile

typedef short v8s __attribute__((ext_vector_type(8)));
typedef float v4f __attribute__((ext_vector_type(4)));

#define LDS_PTR(p) ((__attribute__((address_space(3))) unsigned int*)(p))
#define GLB_PTR(p) ((const __attribute__((address_space(1))) unsigned int*)(p))

__device__ __forceinline__ unsigned short f2bf(float f) {
    union { float f; unsigned u; } v; v.f = f;
    unsigned r = (v.u + 0x7FFFu + ((v.u >> 16) & 1u)) >> 16;
    return (unsigned short)r;
}
// pack two floats -> two truncated bf16 in one dword (lo = a, hi = b)
__device__ __forceinline__ unsigned pk2(float a, float b) {
    union { float f; unsigned u; } x, y; x.f = a; y.f = b;
    return (x.u >> 16) | (y.u & 0xFFFF0000u);
}
__device__ __forceinline__ unsigned pk2r(float a, float b) {
    return (unsigned)f2bf(a) | ((unsigned)f2bf(b) << 16);
}
__device__ __forceinline__ float fexp2(float x) {
#if __has_builtin(__builtin_amdgcn_exp2f)
    return __builtin_amdgcn_exp2f(x);
#else
    return __expf(x * 0.69314718056f);
#endif
}

#define QSCALE 0.18033688011112042f   // 0.125 / ln2  (folded into Wq, bq)

// ---------------------------------------------------------------------------
// x fp32 -> bf16, written TILED: [(m>>7)*12 + (k>>6)][m&127][k&63]
// ---------------------------------------------------------------------------
__global__ __launch_bounds__(256)
void cvt_x_kernel(const float* __restrict__ x, unsigned short* __restrict__ xb) {
    const size_t p = ((size_t)blockIdx.x * 256 + threadIdx.x) * 8;
    const int m = (int)(p / DM);
    const int k = (int)(p % DM);
    const float4 a = *(const float4*)(x + p);
    const float4 b = *(const float4*)(x + p + 4);
    v8s o;
    o[0] = (short)f2bf(a.x); o[1] = (short)f2bf(a.y);
    o[2] = (short)f2bf(a.z); o[3] = (short)f2bf(a.w);
    o[4] = (short)f2bf(b.x); o[5] = (short)f2bf(b.y);
    o[6] = (short)f2bf(b.z); o[7] = (short)f2bf(b.w);
    const size_t dst = ((size_t)(m >> 7) * KT + (k >> 6)) * BRICK + (size_t)(m & 127) * 64 + (k & 63);
    *(v8s*)(xb + dst) = o;
}

// ---------------------------------------------------------------------------
// W[k][n] fp32 -> WT tiled: [(n>>7)*12 + (k>>6)][n&127][k&63] bf16.
// z==0 (Wq) scaled by 0.125/ln2 (exp2 path).
// ---------------------------------------------------------------------------
__global__ __launch_bounds__(256)
void cvt_w_kernel(const float* __restrict__ W0, const float* __restrict__ W1,
                  const float* __restrict__ W2, const float* __restrict__ W3,
                  unsigned short* __restrict__ wt) {
    __shared__ unsigned short T[64][72];
    const int z = blockIdx.z;
    const float* W = (z == 0) ? W0 : (z == 1) ? W1 : (z == 2) ? W2 : W3;
    const float scale = (z == 0) ? QSCALE : 1.0f;
    const int k0 = blockIdx.x * 64, n0 = blockIdx.y * 64;
    const int t = threadIdx.x;
    {
        const int kr = t >> 2;
        const int ns = (t & 3) * 16;
        #pragma unroll
        for (int j = 0; j < 4; ++j) {
            const float4 v = *(const float4*)(W + (size_t)(k0 + kr) * DM + n0 + ns + j * 4);
            T[ns + j * 4 + 0][kr] = f2bf(v.x * scale);
            T[ns + j * 4 + 1][kr] = f2bf(v.y * scale);
            T[ns + j * 4 + 2][kr] = f2bf(v.z * scale);
            T[ns + j * 4 + 3][kr] = f2bf(v.w * scale);
        }
    }
    __syncthreads();
    {
        unsigned short* dst = wt + (size_t)z * DM * DM +
            ((size_t)(n0 >> 7) * KT + (k0 >> 6)) * BRICK + (size_t)(n0 & 64) * 64;
        const int n = t >> 2;
        const int ks = (t & 3) * 16;
        #pragma unroll
        for (int j = 0; j < 2; ++j)
            *(v8s*)(dst + (size_t)n * 64 + ks + j * 8) = *(const v8s*)&T[n][ks + j * 8];
    }
}

// ---------------------------------------------------------------------------
// Fused QKV GEMM: grid (64, 18); yb -> z = yb/6, n-block = yb%6.
// 128x128 tile, BK=64, global_load_lds 16B from TILED operands, XOR swizzle.
// z=0 -> Q[bh][s][d] (pre-scaled), z=1 -> K[bh][s][d], z=2 -> VT[bh][d][s].
// ---------------------------------------------------------------------------
__global__ __launch_bounds__(256)
void gemm_qkv_kernel(const unsigned short* __restrict__ xb, const unsigned short* __restrict__ wtbuf,
                     const float* __restrict__ bq, const float* __restrict__ bk,
                     const float* __restrict__ bv,
                     unsigned short* __restrict__ qb, unsigned short* __restrict__ kb,
                     unsigned short* __restrict__ vtb) {
    __shared__ unsigned short smem[16384];        // As 8192 | Bs 8192
    unsigned short* As = smem;
    unsigned short* Bs = smem + 8192;
    const int yb = blockIdx.y;
    const int z = yb / 6;
    const int N0 = (yb % 6) * 128;                // column within the z-matrix
    const float* bias = (z == 0) ? bq : (z == 1) ? bk : bv;
    const float bscale = (z == 0) ? QSCALE : 1.0f;

    const int t = threadIdx.x;
    const int w = t >> 6, lane = t & 63, quad = lane >> 4, l15 = lane & 15;
    const int wm = w >> 1, wn = w & 1;
    const int M0 = blockIdx.x * 128;

    const unsigned short* gA = xb + ((size_t)(M0 >> 7) * KT) * BRICK;
    const unsigned short* gB = wtbuf + (size_t)yb * (KT * BRICK);   // z-major contiguous bricks

    const int r8 = lane >> 3;
    const int c8 = (lane & 7) ^ r8;
    const int goff = r8 * 64 + c8 * 8;
    const int rl = l15 & 7, rh = l15 >> 3;

    v4f acc[4][4];
    #pragma unroll
    for (int i = 0; i < 4; ++i)
        #pragma unroll
        for (int j = 0; j < 4; ++j) acc[i][j] = (v4f){0, 0, 0, 0};

    for (int kt = 0; kt < KT; ++kt) {
        const unsigned short* ta = gA + kt * BRICK;
        const unsigned short* tb = gB + kt * BRICK;
        __syncthreads();
        #pragma unroll
        for (int u = 0; u < 4; ++u) {
            const int win = w * 4 + u;
            __builtin_amdgcn_global_load_lds(GLB_PTR(ta + win * 512 + goff), LDS_PTR(As + win * 512), 16, 0, 0);
            __builtin_amdgcn_global_load_lds(GLB_PTR(tb + win * 512 + goff), LDS_PTR(Bs + win * 512), 16, 0, 0);
        }
        __syncthreads();
        #pragma unroll
        for (int kc = 0; kc < 2; ++kc) {
            const int cs = ((kc << 2) | quad) ^ rl;
            v8s a[4], b[4];
            #pragma unroll
            for (int i = 0; i < 4; ++i)
                a[i] = *(const v8s*)&As[(wm * 8 + i * 2 + rh) * 512 + rl * 64 + cs * 8];
            #pragma unroll
            for (int j = 0; j < 4; ++j)
                b[j] = *(const v8s*)&Bs[(wn * 8 + j * 2 + rh) * 512 + rl * 64 + cs * 8];
            #pragma unroll
            for (int i = 0; i < 4; ++i)
                #pragma unroll
                for (int j = 0; j < 4; ++j)
                    acc[i][j] = __builtin_amdgcn_mfma_f32_16x16x32_bf16(a[i], b[j], acc[i][j], 0, 0, 0);
        }
    }

    const int b_ = M0 >> 11;
    const int sidx0 = M0 & 2047;
    const int h0 = N0 >> 6;

    if (z < 2) {   // Q/K: [bh][s][64]
        unsigned short* outp = (z == 0) ? qb : kb;
        #pragma unroll
        for (int j = 0; j < 4; ++j) {
            const int n = N0 + wn * 64 + j * 16 + l15;
            const int h = n >> 6, d = n & 63;
            const float bv_ = bias[n] * bscale;
            #pragma unroll
            for (int i = 0; i < 4; ++i)
                #pragma unroll
                for (int r = 0; r < 4; ++r) {
                    const int sidx = sidx0 + wm * 64 + i * 16 + quad * 4 + r;
                    outp[(((size_t)(b_ * HEADS + h) * SEQ + sidx) << 6) + d] = f2bf(acc[i][j][r] + bv_);
                }
        }
    } else {       // V -> VT[bh][d][s], two m-half phases through LDS
        unsigned short* Ts = smem;                 // [128 dloc][72]
        #pragma unroll
        for (int p = 0; p < 2; ++p) {
            __syncthreads();
            if (wm == p) {
                #pragma unroll
                for (int j = 0; j < 4; ++j) {
                    const int dloc = wn * 64 + j * 16 + l15;
                    const float bv_ = bias[N0 + dloc];
                    #pragma unroll
                    for (int i = 0; i < 4; ++i)
                        #pragma unroll
                        for (int r = 0; r < 4; ++r)
                            Ts[dloc * 72 + i * 16 + quad * 4 + r] = f2bf(acc[i][j][r] + bv_);
                }
            }
            __syncthreads();
            const int dloc = t >> 1, ms = (t & 1) * 32;
            const int h = h0 + (dloc >> 6), d = dloc & 63;
            unsigned short* dst = vtb + (((size_t)(b_ * HEADS + h) * DK + d) << 11) + sidx0 + p * 64 + ms;
            #pragma unroll
            for (int jj = 0; jj < 4; ++jj)
                *(v8s*)(dst + jj * 8) = *(const v8s*)&Ts[dloc * 72 + ms + jj * 8];
        }
    }
}

// ---------------------------------------------------------------------------
// Output projection: 128m x 64n tiles, grid (64,12)=768 blocks (3/CU).
// out fp32 [8192][768] = ob(tiled bf16) @ WoT + bo
// ---------------------------------------------------------------------------
__global__ __launch_bounds__(256)
void gemm_out_kernel(const unsigned short* __restrict__ ob, const unsigned short* __restrict__ wto,
                     const float* __restrict__ bias, float* __restrict__ out) {
    __shared__ unsigned short smem[12288];   // As 8192 | Bs 4096
    unsigned short* As = smem;
    unsigned short* Bs = smem + 8192;
    const int t = threadIdx.x;
    const int w = t >> 6, lane = t & 63, quad = lane >> 4, l15 = lane & 15;
    const int wm = w >> 1, wn = w & 1;
    const int M0 = blockIdx.x * 128;
    const int N0 = blockIdx.y * 64;

    const unsigned short* gA = ob + ((size_t)(M0 >> 7) * KT) * BRICK;
    const unsigned short* gB = wto + ((size_t)(N0 >> 7) * KT) * BRICK + (size_t)(N0 & 64) * 64;

    const int r8 = lane >> 3;
    const int c8 = (lane & 7) ^ r8;
    const int goff = r8 * 64 + c8 * 8;
    const int rl = l15 & 7, rh = l15 >> 3;

    v4f acc[4][2];
    #pragma unroll
    for (int i = 0; i < 4; ++i)
        #pragma unroll
        for (int j = 0; j < 2; ++j) acc[i][j] = (v4f){0, 0, 0, 0};

    for (int kt = 0; kt < KT; ++kt) {
        const unsigned short* ta = gA + kt * BRICK;
        const unsigned short* tb = gB + kt * BRICK;
        __syncthreads();
        #pragma unroll
        for (int u = 0; u < 4; ++u) {
            const int win = w * 4 + u;
            __builtin_amdgcn_global_load_lds(GLB_PTR(ta + win * 512 + goff), LDS_PTR(As + win * 512), 16, 0, 0);
        }
        #pragma unroll
        for (int u = 0; u < 2; ++u) {
            const int win = w * 2 + u;
            __builtin_amdgcn_global_load_lds(GLB_PTR(tb + win * 512 + goff), LDS_PTR(Bs + win * 512), 16, 0, 0);
        }
        __syncthreads();
        #pragma unroll
        for (int kc = 0; kc < 2; ++kc) {
            const int cs = ((kc << 2) | quad) ^ rl;
            v8s a[4], b[2];
            #pragma unroll
            for (int i = 0; i < 4; ++i)
                a[i] = *(const v8s*)&As[(wm * 8 + i * 2 + rh) * 512 + rl * 64 + cs * 8];
            #pragma unroll
            for (int j = 0; j < 2; ++j)
                b[j] = *(const v8s*)&Bs[(wn * 4 + j * 2 + rh) * 512 + rl * 64 + cs * 8];
            #pragma unroll
            for (int i = 0; i < 4; ++i)
                #pragma unroll
                for (int j = 0; j < 2; ++j)
                    acc[i][j] = __builtin_amdgcn_mfma_f32_16x16x32_bf16(a[i], b[j], acc[i][j], 0, 0, 0);
        }
    }

    #pragma unroll
    for (int j = 0; j < 2; ++j) {
        const int n = N0 + wn * 32 + j * 16 + l15;
        const float bv_ = bias[n];
        #pragma unroll
        for (int i = 0; i < 4; ++i)
            #pragma unroll
            for (int r = 0; r < 4; ++r) {
                const int m = M0 + wm * 64 + i * 16 + quad * 4 + r;
                out[(size_t)m * DM + n] = acc[i][j][r] + bv_;
            }
    }
}

// ---------------------------------------------------------------------------
// Causal flash attention, S^T formulation (A=K, B=Q -> C = S^T; PV as
// O^T = V^T P^T). Lane's 4 acc values = 4 consecutive keys -> packed b64
// P-stores; epilogue = packed b64 O-stores; lsum is a per-lane scalar.
// Pair-balanced strips (uniform 33 tile-works), shared kf loads, exp2.
// ---------------------------------------------------------------------------
__global__ __launch_bounds__(256, 3)
void attn_kernel(const unsigned short* __restrict__ Q, const unsigned short* __restrict__ K,
                 const unsigned short* __restrict__ VT, unsigned short* __restrict__ O) {
    __shared__ unsigned short Kb[2][64][72];   // [buf][key][dk]
    __shared__ unsigned short Vb[2][64][72];   // [buf][dk][key]
    __shared__ unsigned short Ps[4][16][72];   // [wave][query][key] (P^T round-trip)
    const int t = threadIdx.x;
    const int w = t >> 6, lane = t & 63, quad = lane >> 4, l15 = lane & 15;

    const int idx = blockIdx.x;
    const int xcd = idx & 7;
    const int j   = idx >> 3;                  // 0..95
    const int bh  = xcd + 8 * (j >> 4);        // 0..47
    const int s   = j & 15;                    // pair index
    const int sA  = s, sB = 31 - s;
    const int q0A = sA * 64, q0B = sB * 64;
    const int nkt = sB + 1;
    const size_t kvbase = (size_t)bh * SEQ * DK;

    // Q B-frags (B[k=dk][n=query]): same byte layout as before
    v8s qfA[2], qfB[2];
    #pragma unroll
    for (int c = 0; c < 2; ++c) {
        qfA[c] = *(const v8s*)(Q + kvbase + (size_t)(q0A + w * 16 + l15) * DK + c * 32 + quad * 8);
        qfB[c] = *(const v8s*)(Q + kvbase + (size_t)(q0B + w * 16 + l15) * DK + c * 32 + quad * 8);
    }

    v4f oA[4], oB[4];                          // O^T: [d-quarter][r]; col=query=l15
    #pragma unroll
    for (int nf = 0; nf < 4; ++nf) { oA[nf] = (v4f){0,0,0,0}; oB[nf] = (v4f){0,0,0,0}; }
    float lsA = 0.f, lsB = 0.f;                // per-lane scalar (query = w,l15)

    const int srow = t >> 3;          // 0..31
    const int scol = (t & 7) * 8;     // 0..56

    // preload tile 0
    v8s kr0 = *(const v8s*)(K  + kvbase + (size_t)srow * DK + scol);
    v8s kr1 = *(const v8s*)(K  + kvbase + (size_t)(srow + 32) * DK + scol);
    v8s vr0 = *(const v8s*)(VT + kvbase + ((size_t)srow << 11) + scol);
    v8s vr1 = *(const v8s*)(VT + kvbase + ((size_t)(srow + 32) << 11) + scol);
    *(v8s*)&Kb[0][srow][scol]      = kr0;
    *(v8s*)&Kb[0][srow + 32][scol] = kr1;
    *(v8s*)&Vb[0][srow][scol]      = vr0;
    *(v8s*)&Vb[0][srow + 32][scol] = vr1;
    __syncthreads();

    const int qA = q0A + w * 16 + l15;         // this lane's query rows
    const int qB = q0B + w * 16 + l15;

    for (int kt = 0; kt < nkt; ++kt) {
        const int k0 = kt * 64;
        const int cur = kt & 1;
        if (kt + 1 < nkt) {
            const int kn = k0 + 64;
            kr0 = *(const v8s*)(K  + kvbase + (size_t)(kn + srow) * DK + scol);
            kr1 = *(const v8s*)(K  + kvbase + (size_t)(kn + srow + 32) * DK + scol);
            vr0 = *(const v8s*)(VT + kvbase + ((size_t)srow << 11) + kn + scol);
            vr1 = *(const v8s*)(VT + kvbase + ((size_t)(srow + 32) << 11) + kn + scol);
        }

        const bool actA = (kt <= sA);

        // merged QK: S^T = K . Q^T  (kf loaded once, used by both strips)
        v4f scB[4], scA[4];
        #pragma unroll
        for (int s4 = 0; s4 < 4; ++s4) { scB[s4] = (v4f){0,0,0,0}; scA[s4] = (v4f){0,0,0,0}; }
        #pragma unroll
        for (int c = 0; c < 2; ++c)
            #pragma unroll
            for (int s4 = 0; s4 < 4; ++s4) {
                const v8s kf = *(const v8s*)&Kb[cur][s4 * 16 + l15][c * 32 + quad * 8];
                scB[s4] = __builtin_amdgcn_mfma_f32_16x16x32_bf16(kf, qfB[c], scB[s4], 0, 0, 0);
                if (actA)
                    scA[s4] = __builtin_amdgcn_mfma_f32_16x16x32_bf16(kf, qfA[c], scA[s4], 0, 0, 0);
            }

        // ---- strip B: exp2, packed P^T store, PV ----
        {
            const bool msk = (kt == nkt - 1);
            #pragma unroll
            for (int s4 = 0; s4 < 4; ++s4) {
                float p[4];
                #pragma unroll
                for (int r = 0; r < 4; ++r) {
                    const int key = k0 + s4 * 16 + quad * 4 + r;
                    const float e = fexp2(scB[s4][r]);
                    p[r] = (!msk || key <= qB) ? e : 0.f;
                    lsB += p[r];
                }
                uint2 pkv; pkv.x = pk2(p[0], p[1]); pkv.y = pk2(p[2], p[3]);
                *(uint2*)&Ps[w][l15][s4 * 16 + quad * 4] = pkv;
            }
            #pragma unroll
            for (int kc = 0; kc < 2; ++kc) {
                const v8s pf = *(const v8s*)&Ps[w][l15][kc * 32 + quad * 8];
                #pragma unroll
                for (int nf = 0; nf < 4; ++nf) {
                    const v8s vf = *(const v8s*)&Vb[cur][nf * 16 + l15][kc * 32 + quad * 8];
                    oB[nf] = __builtin_amdgcn_mfma_f32_16x16x32_bf16(vf, pf, oB[nf], 0, 0, 0);
                }
            }
        }

        // ---- strip A ----
        if (actA) {
            const bool msk = (kt == sA);
            #pragma unroll
            for (int s4 = 0; s4 < 4; ++s4) {
                float p[4];
                #pragma unroll
                for (int r = 0; r < 4; ++r) {
                    const int key = k0 + s4 * 16 + quad * 4 + r;
                    const float e = fexp2(scA[s4][r]);
                    p[r] = (!msk || key <= qA) ? e : 0.f;
                    lsA += p[r];
                }
                uint2 pkv; pkv.x = pk2(p[0], p[1]); pkv.y = pk2(p[2], p[3]);
                *(uint2*)&Ps[w][l15][s4 * 16 + quad * 4] = pkv;
            }
            #pragma unroll
            for (int kc = 0; kc < 2; ++kc) {
                const v8s pf = *(const v8s*)&Ps[w][l15][kc * 32 + quad * 8];
                #pragma unroll
                for (int nf = 0; nf < 4; ++nf) {
                    const v8s vf = *(const v8s*)&Vb[cur][nf * 16 + l15][kc * 32 + quad * 8];
                    oA[nf] = __builtin_amdgcn_mfma_f32_16x16x32_bf16(vf, pf, oA[nf], 0, 0, 0);
                }
            }
        }

        if (kt + 1 < nkt) {
            const int nxt = 1 - cur;
            *(v8s*)&Kb[nxt][srow][scol]      = kr0;
            *(v8s*)&Kb[nxt][srow + 32][scol] = kr1;
            *(v8s*)&Vb[nxt][srow][scol]      = vr0;
            *(v8s*)&Vb[nxt][srow + 32][scol] = vr1;
        }
        __syncthreads();
    }

    // lsum lives per-quad-partial: reduce across the 4 quads
    lsA += __shfl_xor(lsA, 16); lsA += __shfl_xor(lsA, 32);
    lsB += __shfl_xor(lsB, 16); lsB += __shfl_xor(lsB, 32);
    const float invA = 1.f / lsA, invB = 1.f / lsB;

    // epilogue: O[query][d], d = nf*16 + quad*4 + r -> packed b64 stores (tiled ob)
    const int b = bh / HEADS, h = bh % HEADS;
    const size_t brA = ((size_t)(b * 16 + (q0A >> 7)) * KT + h) * BRICK;
    const size_t brB = ((size_t)(b * 16 + (q0B >> 7)) * KT + h) * BRICK;
    const int rowlA = (q0A & 127) + w * 16 + l15;
    const int rowlB = (q0B & 127) + w * 16 + l15;
    #pragma unroll
    for (int nf = 0; nf < 4; ++nf) {
        uint2 a2, b2;
        a2.x = pk2r(oA[nf][0] * invA, oA[nf][1] * invA);
        a2.y = pk2r(oA[nf][2] * invA, oA[nf][3] * invA);
        b2.x = pk2r(oB[nf][0] * invB, oB[nf][1] * invB);
        b2.y = pk2r(oB[nf][2] * invB, oB[nf][3] * invB);
        *(uint2*)(O + brA + (size_t)rowlA * 64 + nf * 16 + quad * 4) = a2;
        *(uint2*)(O + brB + (size_t)rowlB * 64 + nf * 16 + quad * 4) = b2;
    }
}

extern "C" void kernel_launch(void* const* d_in, const int* in_sizes, int n_in,
                              void* d_out, int out_size, void* d_ws, size_t ws_size,
                              hipStream_t stream) {
    const float* x  = (const float*)d_in[0];
    const float* Wq = (const float*)d_in[1];
    const float* bq = (const float*)d_in[2];
    const float* Wk = (const float*)d_in[3];
    const float* bk = (const float*)d_in[4];
    const float* Wv = (const float*)d_in[5];
    const float* bv = (const float*)d_in[6];
    const float* Wo = (const float*)d_in[7];
    const float* bo = (const float*)d_in[8];
    float* out = (float*)d_out;

    unsigned short* xb  = (unsigned short*)d_ws;      // tiled [8192][768] bf16; reused as ob
    unsigned short* qb  = xb  + NE;                   // [bh][s][64]
    unsigned short* kb  = qb  + NE;                   // [bh][s][64]
    unsigned short* vtb = kb  + NE;                   // [bh][64][s]
    unsigned short* wt  = vtb + NE;                   // 4 x [768][768] bf16 tiled (q,k,v,o)
    unsigned short* ob  = xb;                         // alias (xb dead after gemm_qkv)

    cvt_x_kernel<<<dim3(NE / (8 * 256)), 256, 0, stream>>>(x, xb);
    cvt_w_kernel<<<dim3(12, 12, 4), 256, 0, stream>>>(Wq, Wk, Wv, Wo, wt);
    gemm_qkv_kernel<<<dim3(64, 18), 256, 0, stream>>>(xb, wt, bq, bk, bv, qb, kb, vtb);
    attn_kernel<<<dim3(768), 256, 0, stream>>>(qb, kb, vtb, ob);
    gemm_out_kernel<<<dim3(64, 12), 256, 0, stream>>>(ob, wt + (size_t)3 * DM * DM, bo, out);
}

// Round 8
// 212.896 us; speedup vs baseline: 1.1789x; 1.1789x over previous
//
#include <hip/hip_runtime.h>
#include <hip/hip_bf16.h>

#define DM    768
#define HEADS 12
#define DK    64
#define SEQ   2048
#define BATCH 4
#define NE    ((size_t)BATCH * SEQ * DM)   // 6,291,456
#define KT    12                           // 768/64 k-tiles per row-block
#define BRICK 8192                         // 128 rows x 64 k shorts per tile

typedef short v8s __attribute__((ext_vector_type(8)));
typedef float v4f __attribute__((ext_vector_type(4)));

#define LDS_PTR(p) ((__attribute__((address_space(3))) unsigned int*)(p))
#define GLB_PTR(p) ((const __attribute__((address_space(1))) unsigned int*)(p))

__device__ __forceinline__ unsigned short f2bf(float f) {
    union { float f; unsigned u; } v; v.f = f;
    unsigned r = (v.u + 0x7FFFu + ((v.u >> 16) & 1u)) >> 16;
    return (unsigned short)r;
}
// pack two floats -> two truncated bf16 in one dword (lo = a, hi = b)
__device__ __forceinline__ unsigned pk2(float a, float b) {
    union { float f; unsigned u; } x, y; x.f = a; y.f = b;
    return (x.u >> 16) | (y.u & 0xFFFF0000u);
}
__device__ __forceinline__ unsigned pk2r(float a, float b) {
    return (unsigned)f2bf(a) | ((unsigned)f2bf(b) << 16);
}
__device__ __forceinline__ float fexp2(float x) {
#if __has_builtin(__builtin_amdgcn_exp2f)
    return __builtin_amdgcn_exp2f(x);
#else
    return __expf(x * 0.69314718056f);
#endif
}

#define QSCALE 0.18033688011112042f   // 0.125 / ln2  (folded into Wq, bq)

// ---------------------------------------------------------------------------
// x fp32 -> bf16, written TILED: [(m>>7)*12 + (k>>6)][m&127][k&63]
// ---------------------------------------------------------------------------
__global__ __launch_bounds__(256)
void cvt_x_kernel(const float* __restrict__ x, unsigned short* __restrict__ xb) {
    const size_t p = ((size_t)blockIdx.x * 256 + threadIdx.x) * 8;
    const int m = (int)(p / DM);
    const int k = (int)(p % DM);
    const float4 a = *(const float4*)(x + p);
    const float4 b = *(const float4*)(x + p + 4);
    v8s o;
    o[0] = (short)f2bf(a.x); o[1] = (short)f2bf(a.y);
    o[2] = (short)f2bf(a.z); o[3] = (short)f2bf(a.w);
    o[4] = (short)f2bf(b.x); o[5] = (short)f2bf(b.y);
    o[6] = (short)f2bf(b.z); o[7] = (short)f2bf(b.w);
    const size_t dst = ((size_t)(m >> 7) * KT + (k >> 6)) * BRICK + (size_t)(m & 127) * 64 + (k & 63);
    *(v8s*)(xb + dst) = o;
}

// ---------------------------------------------------------------------------
// W[k][n] fp32 -> WT tiled: [(n>>7)*12 + (k>>6)][n&127][k&63] bf16.
// z==0 (Wq) scaled by 0.125/ln2 (exp2 path).
// ---------------------------------------------------------------------------
__global__ __launch_bounds__(256)
void cvt_w_kernel(const float* __restrict__ W0, const float* __restrict__ W1,
                  const float* __restrict__ W2, const float* __restrict__ W3,
                  unsigned short* __restrict__ wt) {
    __shared__ unsigned short T[64][72];
    const int z = blockIdx.z;
    const float* W = (z == 0) ? W0 : (z == 1) ? W1 : (z == 2) ? W2 : W3;
    const float scale = (z == 0) ? QSCALE : 1.0f;
    const int k0 = blockIdx.x * 64, n0 = blockIdx.y * 64;
    const int t = threadIdx.x;
    {
        const int kr = t >> 2;
        const int ns = (t & 3) * 16;
        #pragma unroll
        for (int j = 0; j < 4; ++j) {
            const float4 v = *(const float4*)(W + (size_t)(k0 + kr) * DM + n0 + ns + j * 4);
            T[ns + j * 4 + 0][kr] = f2bf(v.x * scale);
            T[ns + j * 4 + 1][kr] = f2bf(v.y * scale);
            T[ns + j * 4 + 2][kr] = f2bf(v.z * scale);
            T[ns + j * 4 + 3][kr] = f2bf(v.w * scale);
        }
    }
    __syncthreads();
    {
        unsigned short* dst = wt + (size_t)z * DM * DM +
            ((size_t)(n0 >> 7) * KT + (k0 >> 6)) * BRICK + (size_t)(n0 & 64) * 64;
        const int n = t >> 2;
        const int ks = (t & 3) * 16;
        #pragma unroll
        for (int j = 0; j < 2; ++j)
            *(v8s*)(dst + (size_t)n * 64 + ks + j * 8) = *(const v8s*)&T[n][ks + j * 8];
    }
}

// ---------------------------------------------------------------------------
// Fused QKV GEMM, single-barrier double-buffered K-loop + XCD swizzle.
// grid 1152 1-D: xcd=idx&7, g=idx>>3; M-block = xcd+8*(g&7), yb = g>>3 (0..17).
// Same-M blocks (sharing A bricks) pin to one XCD -> A stays in XCD L2.
// 128x128 tile, BK=64, global_load_lds 16B, XOR-swizzled LDS, dbuf 64 KB.
// z=0 -> Q[bh][s][d] (pre-scaled), z=1 -> K[bh][s][d], z=2 -> VT[bh][d][s].
// ---------------------------------------------------------------------------
__global__ __launch_bounds__(256)
void gemm_qkv_kernel(const unsigned short* __restrict__ xb, const unsigned short* __restrict__ wtbuf,
                     const float* __restrict__ bq, const float* __restrict__ bk,
                     const float* __restrict__ bv,
                     unsigned short* __restrict__ qb, unsigned short* __restrict__ kb,
                     unsigned short* __restrict__ vtb) {
    __shared__ unsigned short smem[32768];        // As[2] 2x8192 | Bs[2] 2x8192
    const int idx = blockIdx.x;
    const int xcd = idx & 7, g = idx >> 3;
    const int mb = xcd + 8 * (g & 7);             // 0..63
    const int yb = g >> 3;                        // 0..17
    const int z = yb / 6;
    const int N0 = (yb % 6) * 128;
    const float* bias = (z == 0) ? bq : (z == 1) ? bk : bv;
    const float bscale = (z == 0) ? QSCALE : 1.0f;

    const int t = threadIdx.x;
    const int w = t >> 6, lane = t & 63, quad = lane >> 4, l15 = lane & 15;
    const int wm = w >> 1, wn = w & 1;
    const int M0 = mb * 128;

    const unsigned short* gA = xb + (size_t)mb * (KT * BRICK);
    const unsigned short* gB = wtbuf + (size_t)yb * (KT * BRICK);

    const int r8 = lane >> 3;
    const int c8 = (lane & 7) ^ r8;
    const int goff = r8 * 64 + c8 * 8;
    const int rl = l15 & 7, rh = l15 >> 3;

    v4f acc[4][4];
    #pragma unroll
    for (int i = 0; i < 4; ++i)
        #pragma unroll
        for (int j = 0; j < 4; ++j) acc[i][j] = (v4f){0, 0, 0, 0};

    // preload tile 0 into buffer 0
    #pragma unroll
    for (int u = 0; u < 4; ++u) {
        const int win = w * 4 + u;
        __builtin_amdgcn_global_load_lds(GLB_PTR(gA + win * 512 + goff), LDS_PTR(smem + win * 512), 16, 0, 0);
        __builtin_amdgcn_global_load_lds(GLB_PTR(gB + win * 512 + goff), LDS_PTR(smem + 16384 + win * 512), 16, 0, 0);
    }
    __syncthreads();

    for (int kt = 0; kt < KT; ++kt) {
        const int cur = kt & 1;
        // issue async loads for tile kt+1 into the other buffer (overlap compute)
        if (kt + 1 < KT) {
            const unsigned short* ta = gA + (kt + 1) * BRICK;
            const unsigned short* tb = gB + (kt + 1) * BRICK;
            const int nb = (1 - cur) * 8192;
            #pragma unroll
            for (int u = 0; u < 4; ++u) {
                const int win = w * 4 + u;
                __builtin_amdgcn_global_load_lds(GLB_PTR(ta + win * 512 + goff), LDS_PTR(smem + nb + win * 512), 16, 0, 0);
                __builtin_amdgcn_global_load_lds(GLB_PTR(tb + win * 512 + goff), LDS_PTR(smem + 16384 + nb + win * 512), 16, 0, 0);
            }
        }
        const unsigned short* As = smem + cur * 8192;
        const unsigned short* Bs = smem + 16384 + cur * 8192;
        #pragma unroll
        for (int kc = 0; kc < 2; ++kc) {
            const int cs = ((kc << 2) | quad) ^ rl;
            v8s a[4], b[4];
            #pragma unroll
            for (int i = 0; i < 4; ++i)
                a[i] = *(const v8s*)&As[(wm * 8 + i * 2 + rh) * 512 + rl * 64 + cs * 8];
            #pragma unroll
            for (int j = 0; j < 4; ++j)
                b[j] = *(const v8s*)&Bs[(wn * 8 + j * 2 + rh) * 512 + rl * 64 + cs * 8];
            #pragma unroll
            for (int i = 0; i < 4; ++i)
                #pragma unroll
                for (int j = 0; j < 4; ++j)
                    acc[i][j] = __builtin_amdgcn_mfma_f32_16x16x32_bf16(a[i], b[j], acc[i][j], 0, 0, 0);
        }
        __syncthreads();   // drains vmcnt (next-tile loads) + lgkm (this-tile ds reads)
    }

    const int b_ = M0 >> 11;
    const int sidx0 = M0 & 2047;
    const int h0 = N0 >> 6;

    if (z < 2) {   // Q/K: [bh][s][64]
        unsigned short* outp = (z == 0) ? qb : kb;
        #pragma unroll
        for (int j = 0; j < 4; ++j) {
            const int n = N0 + wn * 64 + j * 16 + l15;
            const int h = n >> 6, d = n & 63;
            const float bv_ = bias[n] * bscale;
            #pragma unroll
            for (int i = 0; i < 4; ++i)
                #pragma unroll
                for (int r = 0; r < 4; ++r) {
                    const int sidx = sidx0 + wm * 64 + i * 16 + quad * 4 + r;
                    outp[(((size_t)(b_ * HEADS + h) * SEQ + sidx) << 6) + d] = f2bf(acc[i][j][r] + bv_);
                }
        }
    } else {       // V -> VT[bh][d][s], two m-half phases through LDS
        unsigned short* Ts = smem;                 // [128 dloc][72]
        #pragma unroll
        for (int p = 0; p < 2; ++p) {
            __syncthreads();
            if (wm == p) {
                #pragma unroll
                for (int j = 0; j < 4; ++j) {
                    const int dloc = wn * 64 + j * 16 + l15;
                    const float bv_ = bias[N0 + dloc];
                    #pragma unroll
                    for (int i = 0; i < 4; ++i)
                        #pragma unroll
                        for (int r = 0; r < 4; ++r)
                            Ts[dloc * 72 + i * 16 + quad * 4 + r] = f2bf(acc[i][j][r] + bv_);
                }
            }
            __syncthreads();
            const int dloc = t >> 1, ms = (t & 1) * 32;
            const int h = h0 + (dloc >> 6), d = dloc & 63;
            unsigned short* dst = vtb + (((size_t)(b_ * HEADS + h) * DK + d) << 11) + sidx0 + p * 64 + ms;
            #pragma unroll
            for (int jj = 0; jj < 4; ++jj)
                *(v8s*)(dst + jj * 8) = *(const v8s*)&Ts[dloc * 72 + ms + jj * 8];
        }
    }
}

// ---------------------------------------------------------------------------
// Output projection: 128x128 tiles, dbuf single-barrier K-loop + XCD swizzle.
// grid 384 1-D: xcd=idx&7, g=idx>>3; M-block = xcd+8*(g&7), nb = g>>3 (0..5).
// out fp32 [8192][768] = ob(tiled bf16) @ WoT + bo
// ---------------------------------------------------------------------------
__global__ __launch_bounds__(256)
void gemm_out_kernel(const unsigned short* __restrict__ ob, const unsigned short* __restrict__ wto,
                     const float* __restrict__ bias, float* __restrict__ out) {
    __shared__ unsigned short smem[32768];
    const int idx = blockIdx.x;
    const int xcd = idx & 7, g = idx >> 3;
    const int mb = xcd + 8 * (g & 7);             // 0..63
    const int nb = g >> 3;                        // 0..5
    const int t = threadIdx.x;
    const int w = t >> 6, lane = t & 63, quad = lane >> 4, l15 = lane & 15;
    const int wm = w >> 1, wn = w & 1;
    const int M0 = mb * 128;
    const int N0 = nb * 128;

    const unsigned short* gA = ob + (size_t)mb * (KT * BRICK);
    const unsigned short* gB = wto + (size_t)nb * (KT * BRICK);

    const int r8 = lane >> 3;
    const int c8 = (lane & 7) ^ r8;
    const int goff = r8 * 64 + c8 * 8;
    const int rl = l15 & 7, rh = l15 >> 3;

    v4f acc[4][4];
    #pragma unroll
    for (int i = 0; i < 4; ++i)
        #pragma unroll
        for (int j = 0; j < 4; ++j) acc[i][j] = (v4f){0, 0, 0, 0};

    #pragma unroll
    for (int u = 0; u < 4; ++u) {
        const int win = w * 4 + u;
        __builtin_amdgcn_global_load_lds(GLB_PTR(gA + win * 512 + goff), LDS_PTR(smem + win * 512), 16, 0, 0);
        __builtin_amdgcn_global_load_lds(GLB_PTR(gB + win * 512 + goff), LDS_PTR(smem + 16384 + win * 512), 16, 0, 0);
    }
    __syncthreads();

    for (int kt = 0; kt < KT; ++kt) {
        const int cur = kt & 1;
        if (kt + 1 < KT) {
            const unsigned short* ta = gA + (kt + 1) * BRICK;
            const unsigned short* tb = gB + (kt + 1) * BRICK;
            const int nxt = (1 - cur) * 8192;
            #pragma unroll
            for (int u = 0; u < 4; ++u) {
                const int win = w * 4 + u;
                __builtin_amdgcn_global_load_lds(GLB_PTR(ta + win * 512 + goff), LDS_PTR(smem + nxt + win * 512), 16, 0, 0);
                __builtin_amdgcn_global_load_lds(GLB_PTR(tb + win * 512 + goff), LDS_PTR(smem + 16384 + nxt + win * 512), 16, 0, 0);
            }
        }
        const unsigned short* As = smem + cur * 8192;
        const unsigned short* Bs = smem + 16384 + cur * 8192;
        #pragma unroll
        for (int kc = 0; kc < 2; ++kc) {
            const int cs = ((kc << 2) | quad) ^ rl;
            v8s a[4], b[4];
            #pragma unroll
            for (int i = 0; i < 4; ++i)
                a[i] = *(const v8s*)&As[(wm * 8 + i * 2 + rh) * 512 + rl * 64 + cs * 8];
            #pragma unroll
            for (int j = 0; j < 4; ++j)
                b[j] = *(const v8s*)&Bs[(wn * 8 + j * 2 + rh) * 512 + rl * 64 + cs * 8];
            #pragma unroll
            for (int i = 0; i < 4; ++i)
                #pragma unroll
                for (int j = 0; j < 4; ++j)
                    acc[i][j] = __builtin_amdgcn_mfma_f32_16x16x32_bf16(a[i], b[j], acc[i][j], 0, 0, 0);
        }
        __syncthreads();
    }

    #pragma unroll
    for (int j = 0; j < 4; ++j) {
        const int n = N0 + wn * 64 + j * 16 + l15;
        const float bv_ = bias[n];
        #pragma unroll
        for (int i = 0; i < 4; ++i)
            #pragma unroll
            for (int r = 0; r < 4; ++r) {
                const int m = M0 + wm * 64 + i * 16 + quad * 4 + r;
                out[(size_t)m * DM + n] = acc[i][j][r] + bv_;
            }
    }
}

// ---------------------------------------------------------------------------
// Causal flash attention, S^T formulation (A=K, B=Q -> C = S^T; PV as
// O^T = V^T P^T). Packed b64 P-stores and O-stores; per-lane scalar lsum.
// Pair-balanced strips (uniform 33 tile-works), shared kf loads, exp2.
// ---------------------------------------------------------------------------
__global__ __launch_bounds__(256, 3)
void attn_kernel(const unsigned short* __restrict__ Q, const unsigned short* __restrict__ K,
                 const unsigned short* __restrict__ VT, unsigned short* __restrict__ O) {
    __shared__ unsigned short Kb[2][64][72];   // [buf][key][dk]
    __shared__ unsigned short Vb[2][64][72];   // [buf][dk][key]
    __shared__ unsigned short Ps[4][16][72];   // [wave][query][key] (P^T round-trip)
    const int t = threadIdx.x;
    const int w = t >> 6, lane = t & 63, quad = lane >> 4, l15 = lane & 15;

    const int idx = blockIdx.x;
    const int xcd = idx & 7;
    const int j   = idx >> 3;                  // 0..95
    const int bh  = xcd + 8 * (j >> 4);        // 0..47
    const int s   = j & 15;                    // pair index
    const int sA  = s, sB = 31 - s;
    const int q0A = sA * 64, q0B = sB * 64;
    const int nkt = sB + 1;
    const size_t kvbase = (size_t)bh * SEQ * DK;

    v8s qfA[2], qfB[2];
    #pragma unroll
    for (int c = 0; c < 2; ++c) {
        qfA[c] = *(const v8s*)(Q + kvbase + (size_t)(q0A + w * 16 + l15) * DK + c * 32 + quad * 8);
        qfB[c] = *(const v8s*)(Q + kvbase + (size_t)(q0B + w * 16 + l15) * DK + c * 32 + quad * 8);
    }

    v4f oA[4], oB[4];                          // O^T: [d-quarter][r]; col=query=l15
    #pragma unroll
    for (int nf = 0; nf < 4; ++nf) { oA[nf] = (v4f){0,0,0,0}; oB[nf] = (v4f){0,0,0,0}; }
    float lsA = 0.f, lsB = 0.f;

    const int srow = t >> 3;          // 0..31
    const int scol = (t & 7) * 8;     // 0..56

    v8s kr0 = *(const v8s*)(K  + kvbase + (size_t)srow * DK + scol);
    v8s kr1 = *(const v8s*)(K  + kvbase + (size_t)(srow + 32) * DK + scol);
    v8s vr0 = *(const v8s*)(VT + kvbase + ((size_t)srow << 11) + scol);
    v8s vr1 = *(const v8s*)(VT + kvbase + ((size_t)(srow + 32) << 11) + scol);
    *(v8s*)&Kb[0][srow][scol]      = kr0;
    *(v8s*)&Kb[0][srow + 32][scol] = kr1;
    *(v8s*)&Vb[0][srow][scol]      = vr0;
    *(v8s*)&Vb[0][srow + 32][scol] = vr1;
    __syncthreads();

    const int qA = q0A + w * 16 + l15;
    const int qB = q0B + w * 16 + l15;

    for (int kt = 0; kt < nkt; ++kt) {
        const int k0 = kt * 64;
        const int cur = kt & 1;
        if (kt + 1 < nkt) {
            const int kn = k0 + 64;
            kr0 = *(const v8s*)(K  + kvbase + (size_t)(kn + srow) * DK + scol);
            kr1 = *(const v8s*)(K  + kvbase + (size_t)(kn + srow + 32) * DK + scol);
            vr0 = *(const v8s*)(VT + kvbase + ((size_t)srow << 11) + kn + scol);
            vr1 = *(const v8s*)(VT + kvbase + ((size_t)(srow + 32) << 11) + kn + scol);
        }

        const bool actA = (kt <= sA);

        v4f scB[4], scA[4];
        #pragma unroll
        for (int s4 = 0; s4 < 4; ++s4) { scB[s4] = (v4f){0,0,0,0}; scA[s4] = (v4f){0,0,0,0}; }
        #pragma unroll
        for (int c = 0; c < 2; ++c)
            #pragma unroll
            for (int s4 = 0; s4 < 4; ++s4) {
                const v8s kf = *(const v8s*)&Kb[cur][s4 * 16 + l15][c * 32 + quad * 8];
                scB[s4] = __builtin_amdgcn_mfma_f32_16x16x32_bf16(kf, qfB[c], scB[s4], 0, 0, 0);
                if (actA)
                    scA[s4] = __builtin_amdgcn_mfma_f32_16x16x32_bf16(kf, qfA[c], scA[s4], 0, 0, 0);
            }

        {
            const bool msk = (kt == nkt - 1);
            #pragma unroll
            for (int s4 = 0; s4 < 4; ++s4) {
                float p[4];
                #pragma unroll
                for (int r = 0; r < 4; ++r) {
                    const int key = k0 + s4 * 16 + quad * 4 + r;
                    const float e = fexp2(scB[s4][r]);
                    p[r] = (!msk || key <= qB) ? e : 0.f;
                    lsB += p[r];
                }
                uint2 pkv; pkv.x = pk2(p[0], p[1]); pkv.y = pk2(p[2], p[3]);
                *(uint2*)&Ps[w][l15][s4 * 16 + quad * 4] = pkv;
            }
            #pragma unroll
            for (int kc = 0; kc < 2; ++kc) {
                const v8s pf = *(const v8s*)&Ps[w][l15][kc * 32 + quad * 8];
                #pragma unroll
                for (int nf = 0; nf < 4; ++nf) {
                    const v8s vf = *(const v8s*)&Vb[cur][nf * 16 + l15][kc * 32 + quad * 8];
                    oB[nf] = __builtin_amdgcn_mfma_f32_16x16x32_bf16(vf, pf, oB[nf], 0, 0, 0);
                }
            }
        }

        if (actA) {
            const bool msk = (kt == sA);
            #pragma unroll
            for (int s4 = 0; s4 < 4; ++s4) {
                float p[4];
                #pragma unroll
                for (int r = 0; r < 4; ++r) {
                    const int key = k0 + s4 * 16 + quad * 4 + r;
                    const float e = fexp2(scA[s4][r]);
                    p[r] = (!msk || key <= qA) ? e : 0.f;
                    lsA += p[r];
                }
                uint2 pkv; pkv.x = pk2(p[0], p[1]); pkv.y = pk2(p[2], p[3]);
                *(uint2*)&Ps[w][l15][s4 * 16 + quad * 4] = pkv;
            }
            #pragma unroll
            for (int kc = 0; kc < 2; ++kc) {
                const v8s pf = *(const v8s*)&Ps[w][l15][kc * 32 + quad * 8];
                #pragma unroll
                for (int nf = 0; nf < 4; ++nf) {
                    const v8s vf = *(const v8s*)&Vb[cur][nf * 16 + l15][kc * 32 + quad * 8];
                    oA[nf] = __builtin_amdgcn_mfma_f32_16x16x32_bf16(vf, pf, oA[nf], 0, 0, 0);
                }
            }
        }

        if (kt + 1 < nkt) {
            const int nxt = 1 - cur;
            *(v8s*)&Kb[nxt][srow][scol]      = kr0;
            *(v8s*)&Kb[nxt][srow + 32][scol] = kr1;
            *(v8s*)&Vb[nxt][srow][scol]      = vr0;
            *(v8s*)&Vb[nxt][srow + 32][scol] = vr1;
        }
        __syncthreads();
    }

    lsA += __shfl_xor(lsA, 16); lsA += __shfl_xor(lsA, 32);
    lsB += __shfl_xor(lsB, 16); lsB += __shfl_xor(lsB, 32);
    const float invA = 1.f / lsA, invB = 1.f / lsB;

    const int b = bh / HEADS, h = bh % HEADS;
    const size_t brA = ((size_t)(b * 16 + (q0A >> 7)) * KT + h) * BRICK;
    const size_t brB = ((size_t)(b * 16 + (q0B >> 7)) * KT + h) * BRICK;
    const int rowlA = (q0A & 127) + w * 16 + l15;
    const int rowlB = (q0B & 127) + w * 16 + l15;
    #pragma unroll
    for (int nf = 0; nf < 4; ++nf) {
        uint2 a2, b2;
        a2.x = pk2r(oA[nf][0] * invA, oA[nf][1] * invA);
        a2.y = pk2r(oA[nf][2] * invA, oA[nf][3] * invA);
        b2.x = pk2r(oB[nf][0] * invB, oB[nf][1] * invB);
        b2.y = pk2r(oB[nf][2] * invB, oB[nf][3] * invB);
        *(uint2*)(O + brA + (size_t)rowlA * 64 + nf * 16 + quad * 4) = a2;
        *(uint2*)(O + brB + (size_t)rowlB * 64 + nf * 16 + quad * 4) = b2;
    }
}

extern "C" void kernel_launch(void* const* d_in, const int* in_sizes, int n_in,
                              void* d_out, int out_size, void* d_ws, size_t ws_size,
                              hipStream_t stream) {
    const float* x  = (const float*)d_in[0];
    const float* Wq = (const float*)d_in[1];
    const float* bq = (const float*)d_in[2];
    const float* Wk = (const float*)d_in[3];
    const float* bk = (const float*)d_in[4];
    const float* Wv = (const float*)d_in[5];
    const float* bv = (const float*)d_in[6];
    const float* Wo = (const float*)d_in[7];
    const float* bo = (const float*)d_in[8];
    float* out = (float*)d_out;

    unsigned short* xb  = (unsigned short*)d_ws;      // tiled [8192][768] bf16; reused as ob
    unsigned short* qb  = xb  + NE;                   // [bh][s][64]
    unsigned short* kb  = qb  + NE;                   // [bh][s][64]
    unsigned short* vtb = kb  + NE;                   // [bh][64][s]
    unsigned short* wt  = vtb + NE;                   // 4 x [768][768] bf16 tiled (q,k,v,o)
    unsigned short* ob  = xb;                         // alias (xb dead after gemm_qkv)

    cvt_x_kernel<<<dim3(NE / (8 * 256)), 256, 0, stream>>>(x, xb);
    cvt_w_kernel<<<dim3(12, 12, 4), 256, 0, stream>>>(Wq, Wk, Wv, Wo, wt);
    gemm_qkv_kernel<<<dim3(1152), 256, 0, stream>>>(xb, wt, bq, bk, bv, qb, kb, vtb);
    attn_kernel<<<dim3(768), 256, 0, stream>>>(qb, kb, vtb, ob);
    gemm_out_kernel<<<dim3(384), 256, 0, stream>>>(ob, wt + (size_t)3 * DM * DM, bo, out);
}